// Round 4
// baseline (485.132 us; speedup 1.0000x reference)
//
#include <hip/hip_runtime.h>
#include <cstddef>

// ---------------- problem constants (match reference) ----------------
#define NB   4
#define NN_  6
#define ND_  41
#define NFH  16
#define NFW  44
#define NC   64
#define NX0_ 200
#define NX1_ 200
#define NXY  (NX0_ * NX1_)                 // 40000
#define NCOL (NB * NN_ * ND_ * NFW)        // 43296 columns (16 vertical pixels each)

// workspace: mats (576 floats, padded to 1024) then meta (NCOL int2)
#define META_OFF 1024

// 3x3 inverse via adjugate (validated rounds 1-3: exact for these inputs).
__device__ __forceinline__ void inv3(const float* a, float* inv) {
    float c00 = __fsub_rn(__fmul_rn(a[4], a[8]), __fmul_rn(a[5], a[7]));
    float c01 = __fsub_rn(__fmul_rn(a[5], a[6]), __fmul_rn(a[3], a[8]));
    float c02 = __fsub_rn(__fmul_rn(a[3], a[7]), __fmul_rn(a[4], a[6]));
    float det = __fadd_rn(__fadd_rn(__fmul_rn(a[0], c00), __fmul_rn(a[1], c01)),
                          __fmul_rn(a[2], c02));
    inv[0] = __fdiv_rn(c00, det);
    inv[1] = __fdiv_rn(__fsub_rn(__fmul_rn(a[2], a[7]), __fmul_rn(a[1], a[8])), det);
    inv[2] = __fdiv_rn(__fsub_rn(__fmul_rn(a[1], a[5]), __fmul_rn(a[2], a[4])), det);
    inv[3] = __fdiv_rn(c01, det);
    inv[4] = __fdiv_rn(__fsub_rn(__fmul_rn(a[0], a[8]), __fmul_rn(a[2], a[6])), det);
    inv[5] = __fdiv_rn(__fsub_rn(__fmul_rn(a[2], a[3]), __fmul_rn(a[0], a[5])), det);
    inv[6] = __fdiv_rn(c02, det);
    inv[7] = __fdiv_rn(__fsub_rn(__fmul_rn(a[1], a[6]), __fmul_rn(a[0], a[7])), det);
    inv[8] = __fdiv_rn(__fsub_rn(__fmul_rn(a[0], a[4]), __fmul_rn(a[1], a[3])), det);
}

__global__ void setup_kernel(const float* __restrict__ rots,
                             const float* __restrict__ trans,
                             const float* __restrict__ intrins,
                             const float* __restrict__ post_rots,
                             const float* __restrict__ post_trans,
                             float* __restrict__ mats) {
    int t = threadIdx.x;
    if (t >= NB * NN_) return;
    const float* R  = rots      + t * 9;
    const float* K  = intrins   + t * 9;
    const float* PR = post_rots + t * 9;
    float Kinv[9], Pinv[9];
    inv3(K, Kinv);
    inv3(PR, Pinv);
    float* o = mats + t * 24;
    for (int i = 0; i < 3; ++i)
        for (int k = 0; k < 3; ++k) {
            float s = __fmul_rn(R[i * 3 + 0], Kinv[0 * 3 + k]);
            s = __fadd_rn(s, __fmul_rn(R[i * 3 + 1], Kinv[1 * 3 + k]));
            s = __fadd_rn(s, __fmul_rn(R[i * 3 + 2], Kinv[2 * 3 + k]));
            o[i * 3 + k] = s;
        }
    for (int i = 0; i < 9; ++i) o[9 + i] = Pinv[i];
    o[18] = trans[t * 3 + 0];
    o[19] = trans[t * 3 + 1];
    o[20] = trans[t * 3 + 2];
    o[21] = post_trans[t * 3 + 0];
    o[22] = post_trans[t * 3 + 1];
    o[23] = post_trans[t * 3 + 2];
}

// Voxel flat index, numerics identical to the passing rounds.
__device__ __forceinline__ int compute_idx(int b, int n, int d, int h, int w,
                                           const float* __restrict__ mats) {
    const float* mp = mats + (b * NN_ + n) * 24;

    float u   = (w == NFW - 1) ? 703.0f : (float)((double)w * (703.0 / 43.0));
    float v   = __fmul_rn((float)h, 17.0f);
    float dep = (float)(4 + d);

    float f0 = __fsub_rn(u, mp[21]);
    float f1 = __fsub_rn(v, mp[22]);
    float f2 = __fsub_rn(dep, mp[23]);

    float q0 = __fadd_rn(__fadd_rn(__fmul_rn(mp[9],  f0), __fmul_rn(mp[10], f1)), __fmul_rn(mp[11], f2));
    float q1 = __fadd_rn(__fadd_rn(__fmul_rn(mp[12], f0), __fmul_rn(mp[13], f1)), __fmul_rn(mp[14], f2));
    float q2 = __fadd_rn(__fadd_rn(__fmul_rn(mp[15], f0), __fmul_rn(mp[16], f1)), __fmul_rn(mp[17], f2));

    float r0 = __fmul_rn(q0, q2);
    float r1 = __fmul_rn(q1, q2);

    float g0 = __fadd_rn(__fadd_rn(__fadd_rn(__fmul_rn(mp[0], r0), __fmul_rn(mp[1], r1)), __fmul_rn(mp[2], q2)), mp[18]);
    float g1 = __fadd_rn(__fadd_rn(__fadd_rn(__fmul_rn(mp[3], r0), __fmul_rn(mp[4], r1)), __fmul_rn(mp[5], q2)), mp[19]);
    float g2 = __fadd_rn(__fadd_rn(__fadd_rn(__fmul_rn(mp[6], r0), __fmul_rn(mp[7], r1)), __fmul_rn(mp[8], q2)), mp[20]);

    float s0 = __fdiv_rn(__fsub_rn(g0, -50.0f), 0.5f);
    float s1 = __fdiv_rn(__fsub_rn(g1, -50.0f), 0.5f);
    float s2 = __fdiv_rn(__fsub_rn(g2, -10.0f), 20.0f);
    s0 = fminf(fmaxf(s0, -1e6f), 1e6f);
    s1 = fminf(fmaxf(s1, -1e6f), 1e6f);
    s2 = fminf(fmaxf(s2, -1e6f), 1e6f);
    int i0 = (int)s0;
    int i1 = (int)s1;
    int i2 = (int)s2;
    if (i0 >= 0 && i0 < NX0_ && i1 >= 0 && i1 < NX1_ && i2 >= 0 && i2 < 1)
        return b * NXY + i0 * NX1_ + i1;
    return -1;
}

// Meta: per column {common idx (-1 dropped, -2 irregular), 16-bit h mask}.
// 16-lane group per column, lane = h. All idx math lives here, off the
// streaming kernel's hot path.
__global__ __launch_bounds__(256) void meta_kernel(const float* __restrict__ mats,
                                                   int2* __restrict__ meta) {
    int cid = blockIdx.x * 16 + (threadIdx.x >> 4);   // NCOL = 2706*16
    int l   = threadIdx.x & 15;                       // l == h
    int w = cid % NFW; int t = cid / NFW;
    int d = t % ND_;   t /= ND_;
    int n = t % NN_;   int b = t / NN_;

    int my = compute_idx(b, n, d, l, w, mats);

    unsigned mask = 0;
    int common = -1;
    bool allsame = true;
    #pragma unroll
    for (int h = 0; h < 16; ++h) {
        int v = __shfl(my, h, 16);
        if (v >= 0) {
            mask |= (1u << h);
            if (common < 0) common = v;
            else if (v != common) allsame = false;
        }
    }
    if (l == 0)
        meta[cid] = make_int2(allsame ? common : -2, (int)mask);
}

// Streaming pool: thread = (column, channel-quad, h-half).
// 8 unconditional independent float4 loads + branchless mask-FMA + 4 atomics.
// No idx math, no cold path -> compiler keeps all 8 loads in flight.
__global__ __launch_bounds__(256) void pool8(const float* __restrict__ x,
                                             const int2* __restrict__ meta,
                                             float* __restrict__ out) {
    int t    = blockIdx.x * 256 + threadIdx.x;   // NCOL*32 threads
    int quad = t & 15;
    int hh   = (t >> 4) & 1;
    int col  = t >> 5;

    int2 m = meta[col];
    int idx = m.x;
    if (idx < 0) return;                 // dropped (-1) or irregular (-2)
    unsigned mask = ((unsigned)m.y >> (hh * 8)) & 0xFFu;

    int w  = col % NFW;
    int bd = col / NFW;                  // (b*NN+n)*ND + d
    const float4* xp = (const float4*)
        (x + ((size_t)bd * NFH * NFW + (size_t)(hh * 8) * NFW + w) * NC) + quad;
    const int HS = NFW * (NC / 4);       // float4 stride between h rows

    float4 v[8];
    #pragma unroll
    for (int j = 0; j < 8; ++j) v[j] = xp[j * HS];

    float4 a = make_float4(0.f, 0.f, 0.f, 0.f);
    #pragma unroll
    for (int j = 0; j < 8; ++j) {
        float mm = (mask >> j) & 1u ? 1.0f : 0.0f;   // == reference feats*w
        a.x += v[j].x * mm; a.y += v[j].y * mm;
        a.z += v[j].z * mm; a.w += v[j].w * mm;
    }

    int bb = idx / NXY, xy = idx % NXY;
    float* o = out + ((size_t)(bb * NC + quad * 4)) * NXY + xy;
    atomicAdd(o,           a.x);
    atomicAdd(o + NXY,     a.y);
    atomicAdd(o + 2 * NXY, a.z);
    atomicAdd(o + 3 * NXY, a.w);
}

// Cold safety net for irregular columns (provably none for these inputs):
// recompute per-h idx and scatter all 64 channels. Isolated so its register
// cost never touches pool8.
__global__ __launch_bounds__(256) void fix_irregular(const float* __restrict__ x,
                                                     const float* __restrict__ mats,
                                                     const int2* __restrict__ meta,
                                                     float* __restrict__ out) {
    int col = blockIdx.x * 256 + threadIdx.x;
    if (col >= NCOL) return;
    if (meta[col].x != -2) return;       // never taken for these inputs
    int w = col % NFW; int t = col / NFW;
    int d = t % ND_;   t /= ND_;
    int n = t % NN_;   int b = t / NN_;
    for (int h = 0; h < NFH; ++h) {
        int idx = compute_idx(b, n, d, h, w, mats);
        if (idx < 0) continue;
        size_t p = ((size_t)((b * NN_ + n) * ND_ + d) * NFH + h) * NFW + w;
        int bb = idx / NXY, xy = idx % NXY;
        for (int c = 0; c < NC; ++c)
            atomicAdd(out + ((size_t)(bb * NC + c)) * NXY + xy, x[p * NC + c]);
    }
}

extern "C" void kernel_launch(void* const* d_in, const int* in_sizes, int n_in,
                              void* d_out, int out_size, void* d_ws, size_t ws_size,
                              hipStream_t stream) {
    (void)in_sizes; (void)n_in; (void)out_size; (void)ws_size;
    const float* x          = (const float*)d_in[0];
    const float* rots       = (const float*)d_in[1];
    const float* trans      = (const float*)d_in[2];
    const float* intrins    = (const float*)d_in[3];
    const float* post_rots  = (const float*)d_in[4];
    const float* post_trans = (const float*)d_in[5];
    float* out  = (float*)d_out;
    float* mats = (float*)d_ws;
    int2*  meta = (int2*)((int*)d_ws + META_OFF);

    setup_kernel<<<1, 32, 0, stream>>>(rots, trans, intrins, post_rots, post_trans, mats);
    meta_kernel<<<NCOL / 16, 256, 0, stream>>>(mats, meta);
    hipMemsetAsync(out, 0, (size_t)NB * NC * NXY * sizeof(float), stream);
    pool8<<<NCOL * 32 / 256, 256, 0, stream>>>(x, meta, out);
    fix_irregular<<<(NCOL + 255) / 256, 256, 0, stream>>>(x, mats, meta, out);
}

// Round 5
// 354.956 us; speedup vs baseline: 1.3667x; 1.3667x over previous
//
#include <hip/hip_runtime.h>
#include <cstddef>

// ---------------- problem constants (match reference) ----------------
#define NB   4
#define NN_  6
#define ND_  41
#define NFH  16
#define NFW  44
#define NC   64
#define NX0_ 200
#define NX1_ 200
#define NXY  (NX0_ * NX1_)                 // 40000
#define NVOX (NB * NXY)                    // 160000 cells
#define NCOL (NB * NN_ * ND_ * NFW)        // 43296 columns (16 vertical pixels each)

// ---------------- workspace layout (int32 slots) ----------------
#define MATS_OFF 0                          // 576 floats, padded to 1024
#define META_OFF 1024                       // NCOL int2
#define CNT_OFF  (META_OFF + 2 * NCOL)      // NVOX ints
#define FILL_OFF (CNT_OFF + NVOX)           // NVOX ints (memset together w/ CNT)
#define OFF_OFF  (FILL_OFF + NVOX)          // NVOX ints
#define BSUM_OFF (OFF_OFF + NVOX)           // 1024
#define BOFF_OFF (BSUM_OFF + 1024)          // 1024
#define LIST_OFF (BOFF_OFF + 1024)          // NCOL ints
#define WS_INTS  (LIST_OFF + NCOL)          // ~614K ints = 2.46 MB

// 3x3 inverse via adjugate (validated rounds 1-4: exact for these inputs).
__device__ __forceinline__ void inv3(const float* a, float* inv) {
    float c00 = __fsub_rn(__fmul_rn(a[4], a[8]), __fmul_rn(a[5], a[7]));
    float c01 = __fsub_rn(__fmul_rn(a[5], a[6]), __fmul_rn(a[3], a[8]));
    float c02 = __fsub_rn(__fmul_rn(a[3], a[7]), __fmul_rn(a[4], a[6]));
    float det = __fadd_rn(__fadd_rn(__fmul_rn(a[0], c00), __fmul_rn(a[1], c01)),
                          __fmul_rn(a[2], c02));
    inv[0] = __fdiv_rn(c00, det);
    inv[1] = __fdiv_rn(__fsub_rn(__fmul_rn(a[2], a[7]), __fmul_rn(a[1], a[8])), det);
    inv[2] = __fdiv_rn(__fsub_rn(__fmul_rn(a[1], a[5]), __fmul_rn(a[2], a[4])), det);
    inv[3] = __fdiv_rn(c01, det);
    inv[4] = __fdiv_rn(__fsub_rn(__fmul_rn(a[0], a[8]), __fmul_rn(a[2], a[6])), det);
    inv[5] = __fdiv_rn(__fsub_rn(__fmul_rn(a[2], a[3]), __fmul_rn(a[0], a[5])), det);
    inv[6] = __fdiv_rn(c02, det);
    inv[7] = __fdiv_rn(__fsub_rn(__fmul_rn(a[1], a[6]), __fmul_rn(a[0], a[7])), det);
    inv[8] = __fdiv_rn(__fsub_rn(__fmul_rn(a[0], a[4]), __fmul_rn(a[1], a[3])), det);
}

__global__ void setup_kernel(const float* __restrict__ rots,
                             const float* __restrict__ trans,
                             const float* __restrict__ intrins,
                             const float* __restrict__ post_rots,
                             const float* __restrict__ post_trans,
                             float* __restrict__ mats) {
    int t = threadIdx.x;
    if (t >= NB * NN_) return;
    const float* R  = rots      + t * 9;
    const float* K  = intrins   + t * 9;
    const float* PR = post_rots + t * 9;
    float Kinv[9], Pinv[9];
    inv3(K, Kinv);
    inv3(PR, Pinv);
    float* o = mats + t * 24;
    for (int i = 0; i < 3; ++i)
        for (int k = 0; k < 3; ++k) {
            float s = __fmul_rn(R[i * 3 + 0], Kinv[0 * 3 + k]);
            s = __fadd_rn(s, __fmul_rn(R[i * 3 + 1], Kinv[1 * 3 + k]));
            s = __fadd_rn(s, __fmul_rn(R[i * 3 + 2], Kinv[2 * 3 + k]));
            o[i * 3 + k] = s;
        }
    for (int i = 0; i < 9; ++i) o[9 + i] = Pinv[i];
    o[18] = trans[t * 3 + 0];
    o[19] = trans[t * 3 + 1];
    o[20] = trans[t * 3 + 2];
    o[21] = post_trans[t * 3 + 0];
    o[22] = post_trans[t * 3 + 1];
    o[23] = post_trans[t * 3 + 2];
}

// Voxel flat index, numerics identical to all passing rounds.
__device__ __forceinline__ int compute_idx(int b, int n, int d, int h, int w,
                                           const float* __restrict__ mats) {
    const float* mp = mats + (b * NN_ + n) * 24;

    float u   = (w == NFW - 1) ? 703.0f : (float)((double)w * (703.0 / 43.0));
    float v   = __fmul_rn((float)h, 17.0f);
    float dep = (float)(4 + d);

    float f0 = __fsub_rn(u, mp[21]);
    float f1 = __fsub_rn(v, mp[22]);
    float f2 = __fsub_rn(dep, mp[23]);

    float q0 = __fadd_rn(__fadd_rn(__fmul_rn(mp[9],  f0), __fmul_rn(mp[10], f1)), __fmul_rn(mp[11], f2));
    float q1 = __fadd_rn(__fadd_rn(__fmul_rn(mp[12], f0), __fmul_rn(mp[13], f1)), __fmul_rn(mp[14], f2));
    float q2 = __fadd_rn(__fadd_rn(__fmul_rn(mp[15], f0), __fmul_rn(mp[16], f1)), __fmul_rn(mp[17], f2));

    float r0 = __fmul_rn(q0, q2);
    float r1 = __fmul_rn(q1, q2);

    float g0 = __fadd_rn(__fadd_rn(__fadd_rn(__fmul_rn(mp[0], r0), __fmul_rn(mp[1], r1)), __fmul_rn(mp[2], q2)), mp[18]);
    float g1 = __fadd_rn(__fadd_rn(__fadd_rn(__fmul_rn(mp[3], r0), __fmul_rn(mp[4], r1)), __fmul_rn(mp[5], q2)), mp[19]);
    float g2 = __fadd_rn(__fadd_rn(__fadd_rn(__fmul_rn(mp[6], r0), __fmul_rn(mp[7], r1)), __fmul_rn(mp[8], q2)), mp[20]);

    float s0 = __fdiv_rn(__fsub_rn(g0, -50.0f), 0.5f);
    float s1 = __fdiv_rn(__fsub_rn(g1, -50.0f), 0.5f);
    float s2 = __fdiv_rn(__fsub_rn(g2, -10.0f), 20.0f);
    s0 = fminf(fmaxf(s0, -1e6f), 1e6f);
    s1 = fminf(fmaxf(s1, -1e6f), 1e6f);
    s2 = fminf(fmaxf(s2, -1e6f), 1e6f);
    int i0 = (int)s0;
    int i1 = (int)s1;
    int i2 = (int)s2;
    if (i0 >= 0 && i0 < NX0_ && i1 >= 0 && i1 < NX1_ && i2 >= 0 && i2 < 1)
        return b * NXY + i0 * NX1_ + i1;
    return -1;
}

// Meta + histogram: per column {cell (-1 dropped, -2 irregular), 16-bit mask};
// lane0 of each 16-lane group also bumps count[cell]. All idx math lives here.
__global__ __launch_bounds__(256) void meta_kernel(const float* __restrict__ mats,
                                                   int2* __restrict__ meta,
                                                   int* __restrict__ count) {
    int cid = blockIdx.x * 16 + (threadIdx.x >> 4);   // NCOL = 2706*16
    int l   = threadIdx.x & 15;                       // l == h
    int w = cid % NFW; int t = cid / NFW;
    int d = t % ND_;   t /= ND_;
    int n = t % NN_;   int b = t / NN_;

    int my = compute_idx(b, n, d, l, w, mats);

    unsigned mask = 0;
    int common = -1;
    bool allsame = true;
    #pragma unroll
    for (int h = 0; h < 16; ++h) {
        int v = __shfl(my, h, 16);
        if (v >= 0) {
            mask |= (1u << h);
            if (common < 0) common = v;
            else if (v != common) allsame = false;
        }
    }
    if (l == 0) {
        int cell = (common >= 0 && !allsame) ? -2 : common;
        meta[cid] = make_int2(cell, (int)mask);
        if (cell >= 0) atomicAdd(&count[cell], 1);
    }
}

// Exclusive scan of NVOX counts (3 small kernels, validated in round 1).
__global__ __launch_bounds__(256) void scan1(const int* __restrict__ count,
                                             int* __restrict__ offset,
                                             int* __restrict__ bsum) {
    __shared__ int s[256];
    int tid = threadIdx.x;
    int base = blockIdx.x * 256;
    int v = count[base + tid];
    int acc = v;
    s[tid] = acc;
    __syncthreads();
    for (int o = 1; o < 256; o <<= 1) {
        int add = (tid >= o) ? s[tid - o] : 0;
        __syncthreads();
        acc += add;
        s[tid] = acc;
        __syncthreads();
    }
    offset[base + tid] = acc - v;
    if (tid == 255) bsum[blockIdx.x] = acc;
}

__global__ __launch_bounds__(1024) void scan2(const int* __restrict__ bsum,
                                              int* __restrict__ boff, int nblk) {
    __shared__ int s[1024];
    int tid = threadIdx.x;
    int v = (tid < nblk) ? bsum[tid] : 0;
    int acc = v;
    s[tid] = acc;
    __syncthreads();
    for (int o = 1; o < 1024; o <<= 1) {
        int add = (tid >= o) ? s[tid - o] : 0;
        __syncthreads();
        acc += add;
        s[tid] = acc;
        __syncthreads();
    }
    if (tid < nblk) boff[tid] = acc - v;
}

__global__ __launch_bounds__(256) void scan3(int* __restrict__ offset,
                                             const int* __restrict__ boff) {
    int i = blockIdx.x * 256 + threadIdx.x;
    offset[i] += boff[blockIdx.x];
}

// Bucket columns per cell.
__global__ __launch_bounds__(256) void fill_kernel(const int2* __restrict__ meta,
                                                   const int* __restrict__ offset,
                                                   int* __restrict__ fill,
                                                   int* __restrict__ list) {
    int col = blockIdx.x * 256 + threadIdx.x;
    if (col >= NCOL) return;
    int cell = meta[col].x;
    if (cell < 0) return;
    int pos = atomicAdd(&fill[cell], 1);
    list[offset[cell] + pos] = col;
}

// Gather: one 64-lane wave per cell. lane = (channel-quad, h-segment of 4).
// Per column: 4 independent masked float4 loads (coalesced 1KB/wave), then
// one shfl-xor reduce over segments at the end. Every output element written
// EXACTLY ONCE (zeros for empty cells -> replaces the out memset). No float
// atomics anywhere on the hot path.
__global__ __launch_bounds__(256) void gather_pool(const float* __restrict__ x,
                                                   const int2* __restrict__ meta,
                                                   const int* __restrict__ list,
                                                   const int* __restrict__ offset,
                                                   const int* __restrict__ count,
                                                   float* __restrict__ out) {
    int cell = blockIdx.x * 4 + (threadIdx.x >> 6);   // NVOX = 40000*4
    int lane = threadIdx.x & 63;
    int quad = lane & 15;          // channel quad: channels [4q,4q+4)
    int seg  = lane >> 4;          // h segment: rows [4s,4s+4)

    int off = offset[cell];
    int k   = count[cell];

    float4 acc = make_float4(0.f, 0.f, 0.f, 0.f);
    const int HS = NFW * (NC / 4);                    // float4 stride between h rows

    for (int j = 0; j < k; ++j) {
        int col = list[off + j];
        int2 m  = meta[col];
        unsigned mask = ((unsigned)m.y >> (seg * 4)) & 0xFu;
        int w  = col % NFW;
        int bd = col / NFW;                           // ((b*NN+n)*ND + d)
        const float4* xp = (const float4*)
            (x + ((size_t)bd * (NFH * NFW) + (size_t)(seg * 4) * NFW + w) * NC) + quad;
        float4 v0 = xp[0 * HS];
        float4 v1 = xp[1 * HS];
        float4 v2 = xp[2 * HS];
        float4 v3 = xp[3 * HS];
        float m0 = (mask & 1u) ? 1.f : 0.f;
        float m1 = (mask & 2u) ? 1.f : 0.f;
        float m2 = (mask & 4u) ? 1.f : 0.f;
        float m3 = (mask & 8u) ? 1.f : 0.f;
        acc.x += v0.x * m0; acc.y += v0.y * m0; acc.z += v0.z * m0; acc.w += v0.w * m0;
        acc.x += v1.x * m1; acc.y += v1.y * m1; acc.z += v1.z * m1; acc.w += v1.w * m1;
        acc.x += v2.x * m2; acc.y += v2.y * m2; acc.z += v2.z * m2; acc.w += v2.w * m2;
        acc.x += v3.x * m3; acc.y += v3.y * m3; acc.z += v3.z * m3; acc.w += v3.w * m3;
    }

    // reduce over the 4 h-segments (lanes differing in bits 4-5)
    acc.x += __shfl_xor(acc.x, 16, 64); acc.y += __shfl_xor(acc.y, 16, 64);
    acc.z += __shfl_xor(acc.z, 16, 64); acc.w += __shfl_xor(acc.w, 16, 64);
    acc.x += __shfl_xor(acc.x, 32, 64); acc.y += __shfl_xor(acc.y, 32, 64);
    acc.z += __shfl_xor(acc.z, 32, 64); acc.w += __shfl_xor(acc.w, 32, 64);

    if (seg == 0) {
        int b = cell / NXY, xy = cell % NXY;
        float* o = out + ((size_t)(b * NC + quad * 4)) * NXY + xy;
        o[0]       = acc.x;
        o[NXY]     = acc.y;
        o[2 * NXY] = acc.z;
        o[3 * NXY] = acc.w;
    }
}

// Cold safety net for irregular columns (provably none for these inputs):
// runs AFTER gather (out holds final values), adds via atomics.
__global__ __launch_bounds__(256) void fix_irregular(const float* __restrict__ x,
                                                     const float* __restrict__ mats,
                                                     const int2* __restrict__ meta,
                                                     float* __restrict__ out) {
    int col = blockIdx.x * 256 + threadIdx.x;
    if (col >= NCOL) return;
    if (meta[col].x != -2) return;       // never taken for these inputs
    int w = col % NFW; int t = col / NFW;
    int d = t % ND_;   t /= ND_;
    int n = t % NN_;   int b = t / NN_;
    for (int h = 0; h < NFH; ++h) {
        int idx = compute_idx(b, n, d, h, w, mats);
        if (idx < 0) continue;
        size_t p = ((size_t)((b * NN_ + n) * ND_ + d) * NFH + h) * NFW + w;
        int bb = idx / NXY, xy = idx % NXY;
        for (int c = 0; c < NC; ++c)
            atomicAdd(out + ((size_t)(bb * NC + c)) * NXY + xy, x[p * NC + c]);
    }
}

// Fallback if ws too small: round-3 proven atomic-scatter column kernel.
__global__ __launch_bounds__(256) void col_pool_fb(const float* __restrict__ x,
                                                   const float* __restrict__ mats,
                                                   float* __restrict__ out) {
    int cid  = blockIdx.x * 16 + (threadIdx.x >> 4);
    int l    = threadIdx.x & 15;
    int w = cid % NFW; int t = cid / NFW;
    int d = t % ND_;   t /= ND_;
    int n = t % NN_;   int b = t / NN_;
    int myidx = compute_idx(b, n, d, l, w, mats);
    int idx[16];
    #pragma unroll
    for (int h = 0; h < 16; ++h) idx[h] = __shfl(myidx, h, 16);
    int common = -1; bool allsame = true;
    #pragma unroll
    for (int h = 0; h < 16; ++h)
        if (idx[h] >= 0) { if (common < 0) common = idx[h]; else if (idx[h] != common) allsame = false; }
    if (common < 0) return;
    const float4* xp = (const float4*)
        (x + (((size_t)((b * NN_ + n) * ND_ + d) * NFH) * NFW + w) * NC) + l;
    const int HS = NFW * (NC / 4);
    float4 v[16];
    #pragma unroll
    for (int h = 0; h < 16; ++h) v[h] = xp[h * HS];
    if (allsame) {
        float4 a = make_float4(0.f, 0.f, 0.f, 0.f);
        #pragma unroll
        for (int h = 0; h < 16; ++h) {
            float m = (idx[h] >= 0) ? 1.0f : 0.0f;
            a.x += v[h].x * m; a.y += v[h].y * m; a.z += v[h].z * m; a.w += v[h].w * m;
        }
        int bb = common / NXY, xy = common % NXY;
        float* o = out + ((size_t)(bb * NC + l * 4)) * NXY + xy;
        atomicAdd(o, a.x); atomicAdd(o + NXY, a.y);
        atomicAdd(o + 2 * NXY, a.z); atomicAdd(o + 3 * NXY, a.w);
    } else {
        #pragma unroll
        for (int h = 0; h < 16; ++h)
            if (idx[h] >= 0) {
                int bb = idx[h] / NXY, xy = idx[h] % NXY;
                float* o = out + ((size_t)(bb * NC + l * 4)) * NXY + xy;
                atomicAdd(o, v[h].x); atomicAdd(o + NXY, v[h].y);
                atomicAdd(o + 2 * NXY, v[h].z); atomicAdd(o + 3 * NXY, v[h].w);
            }
    }
}

extern "C" void kernel_launch(void* const* d_in, const int* in_sizes, int n_in,
                              void* d_out, int out_size, void* d_ws, size_t ws_size,
                              hipStream_t stream) {
    (void)in_sizes; (void)n_in; (void)out_size;
    const float* x          = (const float*)d_in[0];
    const float* rots       = (const float*)d_in[1];
    const float* trans      = (const float*)d_in[2];
    const float* intrins    = (const float*)d_in[3];
    const float* post_rots  = (const float*)d_in[4];
    const float* post_trans = (const float*)d_in[5];
    float* out  = (float*)d_out;
    float* mats = (float*)d_ws;
    int*   wsi  = (int*)d_ws;
    int2*  meta = (int2*)(wsi + META_OFF);
    int* count  = wsi + CNT_OFF;
    int* fill   = wsi + FILL_OFF;
    int* offset = wsi + OFF_OFF;
    int* bsum   = wsi + BSUM_OFF;
    int* boff   = wsi + BOFF_OFF;
    int* list   = wsi + LIST_OFF;

    setup_kernel<<<1, 32, 0, stream>>>(rots, trans, intrins, post_rots, post_trans, mats);

    if (ws_size >= (size_t)WS_INTS * 4) {
        hipMemsetAsync(count, 0, (size_t)(2 * NVOX) * 4, stream);   // count+fill
        meta_kernel<<<NCOL / 16, 256, 0, stream>>>(mats, meta, count);
        scan1<<<NVOX / 256, 256, 0, stream>>>(count, offset, bsum);
        scan2<<<1, 1024, 0, stream>>>(bsum, boff, NVOX / 256);
        scan3<<<NVOX / 256, 256, 0, stream>>>(offset, boff);
        fill_kernel<<<(NCOL + 255) / 256, 256, 0, stream>>>(meta, offset, fill, list);
        gather_pool<<<NVOX / 4, 256, 0, stream>>>(x, meta, list, offset, count, out);
        fix_irregular<<<(NCOL + 255) / 256, 256, 0, stream>>>(x, mats, meta, out);
    } else {
        hipMemsetAsync(out, 0, (size_t)NB * NC * NXY * sizeof(float), stream);
        col_pool_fb<<<NCOL / 16, 256, 0, stream>>>(x, mats, out);
    }
}

// Round 6
// 339.092 us; speedup vs baseline: 1.4307x; 1.0468x over previous
//
#include <hip/hip_runtime.h>
#include <cstddef>

// ---------------- problem constants (match reference) ----------------
#define NB   4
#define NN_  6
#define ND_  41
#define NFH  16
#define NFW  44
#define NC   64
#define NX0_ 200
#define NX1_ 200
#define NXY  (NX0_ * NX1_)                 // 40000
#define NVOX (NB * NXY)                    // 160000 cells
#define NCOL (NB * NN_ * ND_ * NFW)        // 43296 columns (16 vertical pixels each)
#define NTILE (NVOX / 64)                  // 2500 tiles of 64 consecutive xy
#define NTILEP 2560                        // padded to 10*256 for the scan

// ---------------- workspace layout (int32 slots) ----------------
#define MATS_OFF 0                          // 576 floats, padded to 1024
#define META_OFF 1024                       // NCOL int2
#define CNT_OFF  (META_OFF + 2 * NCOL)      // NTILEP ints
#define FILL_OFF (CNT_OFF + NTILEP)         // NTILEP ints (memset together w/ CNT)
#define OFF_OFF  (FILL_OFF + NTILEP)        // NTILEP ints
#define BSUM_OFF (OFF_OFF + NTILEP)         // 1024
#define BOFF_OFF (BSUM_OFF + 1024)          // 1024
#define LIST_OFF (BOFF_OFF + 1024)          // NCOL ints
#define WS_INTS  (LIST_OFF + NCOL)          // ~140K ints = 560 KB

// 3x3 inverse via adjugate (validated rounds 1-5: exact for these inputs).
__device__ __forceinline__ void inv3(const float* a, float* inv) {
    float c00 = __fsub_rn(__fmul_rn(a[4], a[8]), __fmul_rn(a[5], a[7]));
    float c01 = __fsub_rn(__fmul_rn(a[5], a[6]), __fmul_rn(a[3], a[8]));
    float c02 = __fsub_rn(__fmul_rn(a[3], a[7]), __fmul_rn(a[4], a[6]));
    float det = __fadd_rn(__fadd_rn(__fmul_rn(a[0], c00), __fmul_rn(a[1], c01)),
                          __fmul_rn(a[2], c02));
    inv[0] = __fdiv_rn(c00, det);
    inv[1] = __fdiv_rn(__fsub_rn(__fmul_rn(a[2], a[7]), __fmul_rn(a[1], a[8])), det);
    inv[2] = __fdiv_rn(__fsub_rn(__fmul_rn(a[1], a[5]), __fmul_rn(a[2], a[4])), det);
    inv[3] = __fdiv_rn(c01, det);
    inv[4] = __fdiv_rn(__fsub_rn(__fmul_rn(a[0], a[8]), __fmul_rn(a[2], a[6])), det);
    inv[5] = __fdiv_rn(__fsub_rn(__fmul_rn(a[2], a[3]), __fmul_rn(a[0], a[5])), det);
    inv[6] = __fdiv_rn(c02, det);
    inv[7] = __fdiv_rn(__fsub_rn(__fmul_rn(a[1], a[6]), __fmul_rn(a[0], a[7])), det);
    inv[8] = __fdiv_rn(__fsub_rn(__fmul_rn(a[0], a[4]), __fmul_rn(a[1], a[3])), det);
}

__global__ void setup_kernel(const float* __restrict__ rots,
                             const float* __restrict__ trans,
                             const float* __restrict__ intrins,
                             const float* __restrict__ post_rots,
                             const float* __restrict__ post_trans,
                             float* __restrict__ mats) {
    int t = threadIdx.x;
    if (t >= NB * NN_) return;
    const float* R  = rots      + t * 9;
    const float* K  = intrins   + t * 9;
    const float* PR = post_rots + t * 9;
    float Kinv[9], Pinv[9];
    inv3(K, Kinv);
    inv3(PR, Pinv);
    float* o = mats + t * 24;
    for (int i = 0; i < 3; ++i)
        for (int k = 0; k < 3; ++k) {
            float s = __fmul_rn(R[i * 3 + 0], Kinv[0 * 3 + k]);
            s = __fadd_rn(s, __fmul_rn(R[i * 3 + 1], Kinv[1 * 3 + k]));
            s = __fadd_rn(s, __fmul_rn(R[i * 3 + 2], Kinv[2 * 3 + k]));
            o[i * 3 + k] = s;
        }
    for (int i = 0; i < 9; ++i) o[9 + i] = Pinv[i];
    o[18] = trans[t * 3 + 0];
    o[19] = trans[t * 3 + 1];
    o[20] = trans[t * 3 + 2];
    o[21] = post_trans[t * 3 + 0];
    o[22] = post_trans[t * 3 + 1];
    o[23] = post_trans[t * 3 + 2];
}

// Voxel flat index, numerics identical to all passing rounds.
__device__ __forceinline__ int compute_idx(int b, int n, int d, int h, int w,
                                           const float* __restrict__ mats) {
    const float* mp = mats + (b * NN_ + n) * 24;

    float u   = (w == NFW - 1) ? 703.0f : (float)((double)w * (703.0 / 43.0));
    float v   = __fmul_rn((float)h, 17.0f);
    float dep = (float)(4 + d);

    float f0 = __fsub_rn(u, mp[21]);
    float f1 = __fsub_rn(v, mp[22]);
    float f2 = __fsub_rn(dep, mp[23]);

    float q0 = __fadd_rn(__fadd_rn(__fmul_rn(mp[9],  f0), __fmul_rn(mp[10], f1)), __fmul_rn(mp[11], f2));
    float q1 = __fadd_rn(__fadd_rn(__fmul_rn(mp[12], f0), __fmul_rn(mp[13], f1)), __fmul_rn(mp[14], f2));
    float q2 = __fadd_rn(__fadd_rn(__fmul_rn(mp[15], f0), __fmul_rn(mp[16], f1)), __fmul_rn(mp[17], f2));

    float r0 = __fmul_rn(q0, q2);
    float r1 = __fmul_rn(q1, q2);

    float g0 = __fadd_rn(__fadd_rn(__fadd_rn(__fmul_rn(mp[0], r0), __fmul_rn(mp[1], r1)), __fmul_rn(mp[2], q2)), mp[18]);
    float g1 = __fadd_rn(__fadd_rn(__fadd_rn(__fmul_rn(mp[3], r0), __fmul_rn(mp[4], r1)), __fmul_rn(mp[5], q2)), mp[19]);
    float g2 = __fadd_rn(__fadd_rn(__fadd_rn(__fmul_rn(mp[6], r0), __fmul_rn(mp[7], r1)), __fmul_rn(mp[8], q2)), mp[20]);

    float s0 = __fdiv_rn(__fsub_rn(g0, -50.0f), 0.5f);
    float s1 = __fdiv_rn(__fsub_rn(g1, -50.0f), 0.5f);
    float s2 = __fdiv_rn(__fsub_rn(g2, -10.0f), 20.0f);
    s0 = fminf(fmaxf(s0, -1e6f), 1e6f);
    s1 = fminf(fmaxf(s1, -1e6f), 1e6f);
    s2 = fminf(fmaxf(s2, -1e6f), 1e6f);
    int i0 = (int)s0;
    int i1 = (int)s1;
    int i2 = (int)s2;
    if (i0 >= 0 && i0 < NX0_ && i1 >= 0 && i1 < NX1_ && i2 >= 0 && i2 < 1)
        return b * NXY + i0 * NX1_ + i1;
    return -1;
}

// Meta + tile histogram: per column {cell (-1 dropped, -2 irregular), mask};
// lane0 bumps count[tile] (tile = cell>>6).
__global__ __launch_bounds__(256) void meta_kernel(const float* __restrict__ mats,
                                                   int2* __restrict__ meta,
                                                   int* __restrict__ count) {
    int cid = blockIdx.x * 16 + (threadIdx.x >> 4);   // NCOL = 2706*16
    int l   = threadIdx.x & 15;                       // l == h
    int w = cid % NFW; int t = cid / NFW;
    int d = t % ND_;   t /= ND_;
    int n = t % NN_;   int b = t / NN_;

    int my = compute_idx(b, n, d, l, w, mats);

    unsigned mask = 0;
    int common = -1;
    bool allsame = true;
    #pragma unroll
    for (int h = 0; h < 16; ++h) {
        int v = __shfl(my, h, 16);
        if (v >= 0) {
            mask |= (1u << h);
            if (common < 0) common = v;
            else if (v != common) allsame = false;
        }
    }
    if (l == 0) {
        int cell = (common >= 0 && !allsame) ? -2 : common;
        meta[cid] = make_int2(cell, (int)mask);
        if (cell >= 0) atomicAdd(&count[cell >> 6], 1);
    }
}

// Exclusive scan of NTILEP counts (3 small kernels; structure validated R1/R5).
__global__ __launch_bounds__(256) void scan1(const int* __restrict__ count,
                                             int* __restrict__ offset,
                                             int* __restrict__ bsum) {
    __shared__ int s[256];
    int tid = threadIdx.x;
    int base = blockIdx.x * 256;
    int v = count[base + tid];
    int acc = v;
    s[tid] = acc;
    __syncthreads();
    for (int o = 1; o < 256; o <<= 1) {
        int add = (tid >= o) ? s[tid - o] : 0;
        __syncthreads();
        acc += add;
        s[tid] = acc;
        __syncthreads();
    }
    offset[base + tid] = acc - v;
    if (tid == 255) bsum[blockIdx.x] = acc;
}

__global__ __launch_bounds__(1024) void scan2(const int* __restrict__ bsum,
                                              int* __restrict__ boff, int nblk) {
    __shared__ int s[1024];
    int tid = threadIdx.x;
    int v = (tid < nblk) ? bsum[tid] : 0;
    int acc = v;
    s[tid] = acc;
    __syncthreads();
    for (int o = 1; o < 1024; o <<= 1) {
        int add = (tid >= o) ? s[tid - o] : 0;
        __syncthreads();
        acc += add;
        s[tid] = acc;
        __syncthreads();
    }
    if (tid < nblk) boff[tid] = acc - v;
}

__global__ __launch_bounds__(256) void scan3(int* __restrict__ offset,
                                             const int* __restrict__ boff) {
    int i = blockIdx.x * 256 + threadIdx.x;
    offset[i] += boff[blockIdx.x];
}

// Bucket columns per tile.
__global__ __launch_bounds__(256) void fill_kernel(const int2* __restrict__ meta,
                                                   const int* __restrict__ offset,
                                                   int* __restrict__ fill,
                                                   int* __restrict__ list) {
    int col = blockIdx.x * 256 + threadIdx.x;
    if (col >= NCOL) return;
    int cell = meta[col].x;
    if (cell < 0) return;
    int tile = cell >> 6;
    int pos = atomicAdd(&fill[tile], 1);
    list[offset[tile] + pos] = col;
}

// Tile gather: one 256-thread block per tile of 64 consecutive xy cells.
// Columns accumulate into a padded LDS tile (64ch x 65), then the block
// streams 64ch x 64xy out with each thread writing one FULL 64B line.
// Every output line written exactly once by one CU -> no write amplification,
// no global float atomics, zeros for empty cells come from the same store.
__global__ __launch_bounds__(256) void tile_pool(const float* __restrict__ x,
                                                 const int2* __restrict__ meta,
                                                 const int* __restrict__ list,
                                                 const int* __restrict__ offset,
                                                 const int* __restrict__ count,
                                                 float* __restrict__ out) {
    __shared__ float acc[NC * 65];            // 16640 B, +1 pad kills 64-stride conflicts
    int tile = blockIdx.x;                    // NTILE = 2500

    for (int i = threadIdx.x; i < NC * 65; i += 256) acc[i] = 0.0f;
    __syncthreads();

    int off = offset[tile];
    int k   = count[tile];

    int wave = threadIdx.x >> 6;
    int lane = threadIdx.x & 63;
    int quad = lane & 15;                     // channel quad: [4q,4q+4)
    int seg  = lane >> 4;                     // h segment: rows [4s,4s+4)
    const int HS = NFW * (NC / 4);            // float4 stride between h rows

    for (int j = wave; j < k; j += 4) {
        int col = list[off + j];
        int2 m  = meta[col];
        int lxy = m.x & 63;                   // cell's slot in the tile
        unsigned mask = ((unsigned)m.y >> (seg * 4)) & 0xFu;
        int w  = col % NFW;
        int bd = col / NFW;                   // ((b*NN+n)*ND + d)
        const float4* xp = (const float4*)
            (x + ((size_t)bd * (NFH * NFW) + (size_t)(seg * 4) * NFW + w) * NC) + quad;
        float4 v0 = xp[0 * HS];
        float4 v1 = xp[1 * HS];
        float4 v2 = xp[2 * HS];
        float4 v3 = xp[3 * HS];
        float m0 = (mask & 1u) ? 1.f : 0.f;
        float m1 = (mask & 2u) ? 1.f : 0.f;
        float m2 = (mask & 4u) ? 1.f : 0.f;
        float m3 = (mask & 8u) ? 1.f : 0.f;
        float4 a;
        a.x = v0.x * m0 + v1.x * m1 + v2.x * m2 + v3.x * m3;
        a.y = v0.y * m0 + v1.y * m1 + v2.y * m2 + v3.y * m3;
        a.z = v0.z * m0 + v1.z * m1 + v2.z * m2 + v3.z * m3;
        a.w = v0.w * m0 + v1.w * m1 + v2.w * m2 + v3.w * m3;

        // reduce over the 4 h-segments
        a.x += __shfl_xor(a.x, 16, 64); a.y += __shfl_xor(a.y, 16, 64);
        a.z += __shfl_xor(a.z, 16, 64); a.w += __shfl_xor(a.w, 16, 64);
        a.x += __shfl_xor(a.x, 32, 64); a.y += __shfl_xor(a.y, 32, 64);
        a.z += __shfl_xor(a.z, 32, 64); a.w += __shfl_xor(a.w, 32, 64);

        if (seg == 0) {                       // 16 lanes hold all 64 channels
            atomicAdd(&acc[(quad * 4 + 0) * 65 + lxy], a.x);
            atomicAdd(&acc[(quad * 4 + 1) * 65 + lxy], a.y);
            atomicAdd(&acc[(quad * 4 + 2) * 65 + lxy], a.z);
            atomicAdd(&acc[(quad * 4 + 3) * 65 + lxy], a.w);
        }
    }
    __syncthreads();

    // stream out: thread -> (channel c, 64B line q); writes 16 consecutive
    // floats = exactly one full 64B line of out.
    int b   = tile / (NTILE / NB);            // 625 tiles per b
    int xy0 = (tile % (NTILE / NB)) * 64;
    int c = threadIdx.x >> 2;
    int q = threadIdx.x & 3;
    float*       obase = out + ((size_t)(b * NC + c)) * NXY + xy0 + q * 16;
    const float* abase = acc + c * 65 + q * 16;
    #pragma unroll
    for (int r = 0; r < 4; ++r) {
        float4 vv = make_float4(abase[r * 4 + 0], abase[r * 4 + 1],
                                abase[r * 4 + 2], abase[r * 4 + 3]);
        *(float4*)(obase + r * 4) = vv;       // 16B-aligned: all offsets %4==0 floats
    }
}

// Cold safety net for irregular columns (provably none for these inputs):
// runs AFTER tile_pool (out holds final values), adds via global atomics.
__global__ __launch_bounds__(256) void fix_irregular(const float* __restrict__ x,
                                                     const float* __restrict__ mats,
                                                     const int2* __restrict__ meta,
                                                     float* __restrict__ out) {
    int col = blockIdx.x * 256 + threadIdx.x;
    if (col >= NCOL) return;
    if (meta[col].x != -2) return;       // never taken for these inputs
    int w = col % NFW; int t = col / NFW;
    int d = t % ND_;   t /= ND_;
    int n = t % NN_;   int b = t / NN_;
    for (int h = 0; h < NFH; ++h) {
        int idx = compute_idx(b, n, d, h, w, mats);
        if (idx < 0) continue;
        size_t p = ((size_t)((b * NN_ + n) * ND_ + d) * NFH + h) * NFW + w;
        int bb = idx / NXY, xy = idx % NXY;
        for (int c = 0; c < NC; ++c)
            atomicAdd(out + ((size_t)(bb * NC + c)) * NXY + xy, x[p * NC + c]);
    }
}

// Fallback if ws too small: round-3 proven atomic-scatter column kernel.
__global__ __launch_bounds__(256) void col_pool_fb(const float* __restrict__ x,
                                                   const float* __restrict__ mats,
                                                   float* __restrict__ out) {
    int cid  = blockIdx.x * 16 + (threadIdx.x >> 4);
    int l    = threadIdx.x & 15;
    int w = cid % NFW; int t = cid / NFW;
    int d = t % ND_;   t /= ND_;
    int n = t % NN_;   int b = t / NN_;
    int myidx = compute_idx(b, n, d, l, w, mats);
    int idx[16];
    #pragma unroll
    for (int h = 0; h < 16; ++h) idx[h] = __shfl(myidx, h, 16);
    int common = -1; bool allsame = true;
    #pragma unroll
    for (int h = 0; h < 16; ++h)
        if (idx[h] >= 0) { if (common < 0) common = idx[h]; else if (idx[h] != common) allsame = false; }
    if (common < 0) return;
    const float4* xp = (const float4*)
        (x + (((size_t)((b * NN_ + n) * ND_ + d) * NFH) * NFW + w) * NC) + l;
    const int HS = NFW * (NC / 4);
    float4 v[16];
    #pragma unroll
    for (int h = 0; h < 16; ++h) v[h] = xp[h * HS];
    if (allsame) {
        float4 a = make_float4(0.f, 0.f, 0.f, 0.f);
        #pragma unroll
        for (int h = 0; h < 16; ++h) {
            float m = (idx[h] >= 0) ? 1.0f : 0.0f;
            a.x += v[h].x * m; a.y += v[h].y * m; a.z += v[h].z * m; a.w += v[h].w * m;
        }
        int bb = common / NXY, xy = common % NXY;
        float* o = out + ((size_t)(bb * NC + l * 4)) * NXY + xy;
        atomicAdd(o, a.x); atomicAdd(o + NXY, a.y);
        atomicAdd(o + 2 * NXY, a.z); atomicAdd(o + 3 * NXY, a.w);
    } else {
        #pragma unroll
        for (int h = 0; h < 16; ++h)
            if (idx[h] >= 0) {
                int bb = idx[h] / NXY, xy = idx[h] % NXY;
                float* o = out + ((size_t)(bb * NC + l * 4)) * NXY + xy;
                atomicAdd(o, v[h].x); atomicAdd(o + NXY, v[h].y);
                atomicAdd(o + 2 * NXY, v[h].z); atomicAdd(o + 3 * NXY, v[h].w);
            }
    }
}

extern "C" void kernel_launch(void* const* d_in, const int* in_sizes, int n_in,
                              void* d_out, int out_size, void* d_ws, size_t ws_size,
                              hipStream_t stream) {
    (void)in_sizes; (void)n_in; (void)out_size;
    const float* x          = (const float*)d_in[0];
    const float* rots       = (const float*)d_in[1];
    const float* trans      = (const float*)d_in[2];
    const float* intrins    = (const float*)d_in[3];
    const float* post_rots  = (const float*)d_in[4];
    const float* post_trans = (const float*)d_in[5];
    float* out  = (float*)d_out;
    float* mats = (float*)d_ws;
    int*   wsi  = (int*)d_ws;
    int2*  meta = (int2*)(wsi + META_OFF);
    int* count  = wsi + CNT_OFF;
    int* fill   = wsi + FILL_OFF;
    int* offset = wsi + OFF_OFF;
    int* bsum   = wsi + BSUM_OFF;
    int* boff   = wsi + BOFF_OFF;
    int* list   = wsi + LIST_OFF;

    setup_kernel<<<1, 32, 0, stream>>>(rots, trans, intrins, post_rots, post_trans, mats);

    if (ws_size >= (size_t)WS_INTS * 4) {
        hipMemsetAsync(count, 0, (size_t)(2 * NTILEP) * 4, stream);   // count+fill
        meta_kernel<<<NCOL / 16, 256, 0, stream>>>(mats, meta, count);
        scan1<<<NTILEP / 256, 256, 0, stream>>>(count, offset, bsum);
        scan2<<<1, 1024, 0, stream>>>(bsum, boff, NTILEP / 256);
        scan3<<<NTILEP / 256, 256, 0, stream>>>(offset, boff);
        fill_kernel<<<(NCOL + 255) / 256, 256, 0, stream>>>(meta, offset, fill, list);
        tile_pool<<<NTILE, 256, 0, stream>>>(x, meta, list, offset, count, out);
        fix_irregular<<<(NCOL + 255) / 256, 256, 0, stream>>>(x, mats, meta, out);
    } else {
        hipMemsetAsync(out, 0, (size_t)NB * NC * NXY * sizeof(float), stream);
        col_pool_fb<<<NCOL / 16, 256, 0, stream>>>(x, mats, out);
    }
}